// Round 15
// baseline (3060.193 us; speedup 1.0000x reference)
//
#include <hip/hip_runtime.h>
#include <hip/hip_bf16.h>

// FF_27650999451977: 2-layer gated RNN (MGU), SEQ=512, B=64, H=IN=512, FP32 I/O.
// Round-15: ping-pong pipelined polling. Two sweep buffers in flight; checking
// buffer A only drains A's loads (vmcnt(32)) while B stays outstanding ->
// detection quantization ~RT/2 instead of ~RT. s_sleep removed from hot polls.
// L1's own-history h: single non-polling sweep hidden under the x-poll flight.
// Everything else = r14 (stamped LLC protocol, double-buffered part, 2 barriers,
// RING=16, bounded spins, coop-launch return check).

#define SEQn 512
#define Bn   64
#define Hn   512
#define RING 16
#define BH   32768      // Bn*Hn dwords
#define TILE 8192       // 16*512 dwords

#define SPIN_MAIN 262144u

typedef __bf16 bf16x8 __attribute__((ext_vector_type(8)));
typedef float  f32x4  __attribute__((ext_vector_type(4)));
typedef unsigned u32;

__device__ __forceinline__ u32 cload(const u32* p) {
    return __hip_atomic_load(p, __ATOMIC_RELAXED, __HIP_MEMORY_SCOPE_AGENT);
}
__device__ __forceinline__ void cstore(u32* p, u32 v) {
    __hip_atomic_store(p, v, __ATOMIC_RELAXED, __HIP_MEMORY_SCOPE_AGENT);
}
__device__ __forceinline__ unsigned short f2bf(float f) {
    u32 u = __float_as_uint(f);
    u += 0x7FFFu + ((u >> 16) & 1u);   // round-to-nearest-even
    return (unsigned short)(u >> 16);
}
__device__ __forceinline__ bf16x8 cvt8(const float* p) {
    bf16x8 r;
#pragma unroll
    for (int i = 0; i < 8; ++i) r[i] = (__bf16)p[i];
    return r;
}

__global__ void __launch_bounds__(256, 1)
rnn_persistent(const float* __restrict__ x,
               const float* __restrict__ Wjx, const float* __restrict__ bjx,
               const float* __restrict__ Wjh, const float* __restrict__ bjh,
               const float* __restrict__ Wkx, const float* __restrict__ bkx,
               const float* __restrict__ Wkh, const float* __restrict__ bkh,
               float* __restrict__ out,   // [SEQ][B][H] outputs + [2][B][H] hidden
               u32* __restrict__ ring0,   // ws: [RING][B][H] stamped L0 h
               u32* __restrict__ ring1,   // ws: [RING][B][H] stamped L1 h
               u32* __restrict__ flags)   // ws: [4][32] L1 x-consumption progress
{
    const int wg    = blockIdx.x;
    const int layer = wg >> 7;       // 0..1
    const int id    = wg & 127;
    const int mg    = id >> 5;       // 0..3  (16 batch rows each)
    const int ng    = id & 31;       // 0..31 (16 output units each)
    const int tid   = threadIdx.x;
    const int wave  = tid >> 6;      // 0..3  (waves 0,1 = x-side, 2,3 = h-side)
    const int lane  = tid & 63;

    // ---- stationary weights -> bf16 VGPR frags (B-operand: col = lane&15) ----
    const int ucol = ng * 16 + (lane & 15);
    const int koff = (wave & 1) * 256 + ((lane >> 4) << 3);
    const float* wjsrc = ((wave < 2) ? Wjx : Wjh) + (size_t)layer * Hn * Hn + (size_t)ucol * Hn + koff;
    const float* wksrc = ((wave < 2) ? Wkx : Wkh) + (size_t)layer * Hn * Hn + (size_t)ucol * Hn + koff;
    bf16x8 wj[8], wk[8];
#pragma unroll
    for (int kt = 0; kt < 8; ++kt) {
        wj[kt] = cvt8(wjsrc + kt * 32);
        wk[kt] = cvt8(wksrc + kt * 32);
    }

    // ---- epilogue constants: thread tid -> output (row ml, unit nu) ----
    const int ml = tid >> 4;
    const int nu = tid & 15;
    const int ue = ng * 16 + nu;
    const int be = mg * 16 + ml;
    const float bje = bjx[layer * Hn + ue] + bjh[layer * Hn + ue];
    const float bke = bkx[layer * Hn + ue] + bkh[layer * Hn + ue];

    __shared__ float part[2][4][2][16][16];   // 16 KB, double-buffered by t&1
    __shared__ char  xT[16384];
    __shared__ char  hT[16384];

    const int m = mg * 16 + (lane & 15);

    auto compute_global = [&](const float* Abase, int pb) {
        f32x4 aj = {0.f, 0.f, 0.f, 0.f}, ak = {0.f, 0.f, 0.f, 0.f};
        const float* arow = Abase + (size_t)m * Hn + koff;
#pragma unroll
        for (int kt = 0; kt < 8; ++kt) {
            bf16x8 af = cvt8(arow + kt * 32);
            aj = __builtin_amdgcn_mfma_f32_16x16x32_bf16(af, wj[kt], aj, 0, 0, 0);
            ak = __builtin_amdgcn_mfma_f32_16x16x32_bf16(af, wk[kt], ak, 0, 0, 0);
        }
#pragma unroll
        for (int r = 0; r < 4; ++r) {
            part[pb][wave][0][((lane >> 4) << 2) + r][lane & 15] = aj[r];
            part[pb][wave][1][((lane >> 4) << 2) + r][lane & 15] = ak[r];
        }
    };
    auto compute_lds = [&](const char* tile, int pb) {
        f32x4 aj = {0.f, 0.f, 0.f, 0.f}, ak = {0.f, 0.f, 0.f, 0.f};
        const int r       = lane & 15;
        const int cb      = ((wave & 1) << 8) + ((lane >> 4) << 3);
        const int swz     = (r & 7) << 4;
        const int rowbase = r << 10;
#pragma unroll
        for (int kt = 0; kt < 8; ++kt) {
            const int c = cb + kt * 32;
            bf16x8 af = *(const bf16x8*)(tile + ((rowbase + (c << 1)) ^ swz));
            aj = __builtin_amdgcn_mfma_f32_16x16x32_bf16(af, wj[kt], aj, 0, 0, 0);
            ak = __builtin_amdgcn_mfma_f32_16x16x32_bf16(af, wk[kt], ak, 0, 0, 0);
        }
#pragma unroll
        for (int r2 = 0; r2 < 4; ++r2) {
            part[pb][wave][0][((lane >> 4) << 2) + r2][lane & 15] = aj[r2];
            part[pb][wave][1][((lane >> 4) << 2) + r2][lane & 15] = ak[r2];
        }
    };
    auto zero_store = [&](int pb) {
#pragma unroll
        for (int r2 = 0; r2 < 4; ++r2) {
            part[pb][wave][0][((lane >> 4) << 2) + r2][lane & 15] = 0.f;
            part[pb][wave][1][((lane >> 4) << 2) + r2][lane & 15] = 0.f;
        }
    };

    // ---- poll helpers (ping-pong pipelined) ----
    auto issue = [&](u32 v[32], const u32* src) {
#pragma unroll
        for (int b = 0; b < 32; ++b) v[b] = cload(src + (b << 8) + tid);
    };
    auto pass = [&](const u32 v[32], u32 want) -> bool {
        bool ok = true;
#pragma unroll
        for (int b = 0; b < 32; ++b) ok &= ((v[b] & 0xFFFFu) == want);
        return __all(ok);
    };

    float hprev = 0.f;   // this thread's own h(be,ue) — exact fp32, in register

    for (int t = 0; t < SEQn; ++t) {
        const int pb    = t & 1;
        const int slot  = t & (RING - 1);
        const int pslot = (t - 1) & (RING - 1);
        const u32* hsrc = (layer == 0 ? ring0 : ring1)
                          + (size_t)pslot * BH + mg * TILE;
        const u32* xsrc = ring0 + (size_t)slot * BH + mg * TILE;

        // layer-0 x-side: static input; overlaps the store-visibility window.
        if (layer == 0 && wave < 2)
            compute_global(x + (size_t)t * BH, pb);

        if (layer == 0) {
            if (t > 0) {
                // ping-pong poll of the fresh h tile, back-pressure folded in
                const u32* fp = flags + (mg << 5) + (lane & 31);
                const int bwant = t - RING + 1;
                const u32 want = (u32)t;
                u32 va[32], vb[32];
                issue(va, hsrc); int fa = (int)cload(fp);
                issue(vb, hsrc); int fb = (int)cload(fp);
                u32 it = 0;
                while (true) {
                    if (pass(va, want) && __all(fa >= bwant)) {
#pragma unroll
                        for (int b = 0; b < 32; ++b) {
                            const int d = (b << 8) + tid, r = d >> 9;
                            *(unsigned short*)(hT + ((d << 1) ^ ((r & 7) << 4))) =
                                (unsigned short)(va[b] >> 16);
                        }
                        break;
                    }
                    issue(va, hsrc); fa = (int)cload(fp);
                    if (pass(vb, want) && __all(fb >= bwant)) {
#pragma unroll
                        for (int b = 0; b < 32; ++b) {
                            const int d = (b << 8) + tid, r = d >> 9;
                            *(unsigned short*)(hT + ((d << 1) ^ ((r & 7) << 4))) =
                                (unsigned short)(vb[b] >> 16);
                        }
                        break;
                    }
                    issue(vb, hsrc); fb = (int)cload(fp);
                    if (++it > SPIN_MAIN) break;      // bounded: fail visibly
                }
            }
        } else {
            // L1: issue x ping-pong first, then read own-history h (1 sweep,
            // verified with a bounded loop that exits in ~1 iteration) while
            // the x sweeps are in flight.
            const u32 xw = (u32)(t + 1), hw = (u32)t;
            u32 xa[32], xb[32], vh[32];
            issue(xa, xsrc);
            issue(xb, xsrc);
            issue(vh, hsrc);
            u32 it = 0;
            while (!pass(vh, hw)) {
                if (++it > SPIN_MAIN) break;
                issue(vh, hsrc);
            }
#pragma unroll
            for (int b = 0; b < 32; ++b) {
                const int d = (b << 8) + tid, r = d >> 9;
                *(unsigned short*)(hT + ((d << 1) ^ ((r & 7) << 4))) =
                    (unsigned short)(vh[b] >> 16);
            }
            it = 0;
            while (true) {
                if (pass(xa, xw)) {
#pragma unroll
                    for (int b = 0; b < 32; ++b) {
                        const int d = (b << 8) + tid, r = d >> 9;
                        *(unsigned short*)(xT + ((d << 1) ^ ((r & 7) << 4))) =
                            (unsigned short)(xa[b] >> 16);
                    }
                    break;
                }
                issue(xa, xsrc);
                if (pass(xb, xw)) {
#pragma unroll
                    for (int b = 0; b < 32; ++b) {
                        const int d = (b << 8) + tid, r = d >> 9;
                        *(unsigned short*)(xT + ((d << 1) ^ ((r & 7) << 4))) =
                            (unsigned short)(xb[b] >> 16);
                    }
                    break;
                }
                issue(xb, xsrc);
                if (++it > SPIN_MAIN) break;
            }
        }
        __syncthreads();   // A: tiles staged

        if (layer == 1 && tid == 0)
            cstore(flags + (mg << 5) + ng, (u32)(t + 1));

        if (layer == 0) { if (wave >= 2) { if (t > 0) compute_lds(hT, pb); else zero_store(pb); } }
        else            { if (wave < 2) compute_lds(xT, pb); else compute_lds(hT, pb); }
        __syncthreads();   // B: part[pb] complete

        // ---- epilogue ----
        float sj = part[pb][0][0][ml][nu] + part[pb][1][0][ml][nu] +
                   part[pb][2][0][ml][nu] + part[pb][3][0][ml][nu] + bje;
        float sk = part[pb][0][1][ml][nu] + part[pb][1][1][ml][nu] +
                   part[pb][2][1][ml][nu] + part[pb][3][1][ml][nu] + bke;
        float jj = 1.f / (1.f + __expf(-sj));
        float kk = 1.f / (1.f + __expf(-sk));
        float hnew = jj * (1.f - hprev) + (1.f - kk) * hprev;
        hprev = hnew;

        // self-publishing stamped store (write-through to LLC)
        u32 word = ((u32)f2bf(hnew) << 16) | (u32)(t + 1);
        cstore((layer == 0 ? ring0 : ring1) + (size_t)slot * BH + (size_t)be * Hn + ue, word);

        if (layer == 1)
            out[(size_t)t * BH + (size_t)be * Hn + ue] = hnew;
        if (t == SEQn - 1)
            out[(size_t)SEQn * BH + (size_t)layer * BH + (size_t)be * Hn + ue] = hnew;
        // no barrier C: part[] double-buffered; tile writes happen post-B next iter
    }
}

extern "C" void kernel_launch(void* const* d_in, const int* in_sizes, int n_in,
                              void* d_out, int out_size, void* d_ws, size_t ws_size,
                              hipStream_t stream) {
    (void)in_sizes; (void)n_in; (void)out_size; (void)ws_size;

    const float* x   = (const float*)d_in[0];
    const float* Wjx = (const float*)d_in[1];
    const float* bjx = (const float*)d_in[2];
    const float* Wjh = (const float*)d_in[3];
    const float* bjh = (const float*)d_in[4];
    const float* Wkx = (const float*)d_in[5];
    const float* bkx = (const float*)d_in[6];
    const float* Wkh = (const float*)d_in[7];
    const float* bkh = (const float*)d_in[8];
    float* out = (float*)d_out;

    char* ws = (char*)d_ws;
    u32* ring0 = (u32*)ws;                       // RING*128KB = 2 MB (stamped)
    u32* ring1 = (u32*)(ws + 2097152);           // 2 MB (stamped)
    u32* flags = (u32*)(ws + 4194304);           // 512 B (pad to 4 KB)

    hipMemsetAsync(ws, 0, 4194304 + 4096, stream);

    void* args[] = { (void*)&x, (void*)&Wjx, (void*)&bjx, (void*)&Wjh, (void*)&bjh,
                     (void*)&Wkx, (void*)&bkx, (void*)&Wkh, (void*)&bkh,
                     (void*)&out, (void*)&ring0, (void*)&ring1, (void*)&flags };
    hipError_t err = hipLaunchCooperativeKernel((void*)rnn_persistent, dim3(256),
                                                dim3(256), args, 0, stream);
    if (err != hipSuccess) {
        // 256 blocks at 1 block/CU on 256 CUs are co-resident; spins are bounded.
        hipLaunchKernelGGL(rnn_persistent, dim3(256), dim3(256), 0, stream,
                           x, Wjx, bjx, Wjh, bjh, Wkx, bkx, Wkh, bkh,
                           out, ring0, ring1, flags);
    }
}